// Round 7
// baseline (449.256 us; speedup 1.0000x reference)
//
#include <hip/hip_runtime.h>
#include <hip/hip_cooperative_groups.h>
#include <math.h>

namespace cg = cooperative_groups;

typedef __bf16 bf16x8 __attribute__((ext_vector_type(8)));
typedef _Float16 f16x8 __attribute__((ext_vector_type(8)));
typedef _Float16 f16x4 __attribute__((ext_vector_type(4)));
typedef float f32x4 __attribute__((ext_vector_type(4)));

#define LOG2E 1.44269504f
#define TWOL2E 2.88539008f
#define TSTEPS 256

__device__ __forceinline__ unsigned short f2bf(float f) {
  unsigned int u = __builtin_bit_cast(unsigned int, f);
  u += 0x7fffu + ((u >> 16) & 1u);
  return (unsigned short)(u >> 16);
}
__device__ __forceinline__ unsigned int pack2bf(float a, float b) {
  return (unsigned int)f2bf(a) | ((unsigned int)f2bf(b) << 16);
}

__device__ __forceinline__ float qb0(float x) {
  return __builtin_bit_cast(float, __builtin_amdgcn_mov_dpp(__builtin_bit_cast(int, x), 0x00, 0xf, 0xf, true));
}
__device__ __forceinline__ float qb1(float x) {
  return __builtin_bit_cast(float, __builtin_amdgcn_mov_dpp(__builtin_bit_cast(int, x), 0x55, 0xf, 0xf, true));
}
__device__ __forceinline__ float qb2(float x) {
  return __builtin_bit_cast(float, __builtin_amdgcn_mov_dpp(__builtin_bit_cast(int, x), 0xAA, 0xf, 0xf, true));
}
__device__ __forceinline__ float qb3(float x) {
  return __builtin_bit_cast(float, __builtin_amdgcn_mov_dpp(__builtin_bit_cast(int, x), 0xFF, 0xf, 0xf, true));
}

// ---------- shared memory layout (union across phases) ----------
struct SmemG {                      // GEMM phases
  unsigned short Wt[64][136];       // 64 rows x BK=128 (+8 pad)
  unsigned short Xt[16][136];       // 16 batches x BK=128
  float racc[4][64][4];             // K-group partial-acc merge
};
struct SmemL {                      // LSTM phase
  _Float16 hbuf[2][128];
  float xrow[TSTEPS];
  float red[128];
};
union SmemU { SmemG g; SmemL l; };

// ---------- GEMM phase (device): 64 rows x 16 batches, 512 threads ----------
// 8 waves = 4 row-groups x 2 K-groups; BK=128 staged per iter (half the
// barrier count of the R22 kernel); register double-buffer prefetch.
// W is always fp32; X fp32 (gemm1) or bf16 (gemm2). Epilogue merges the two
// K-group partials via LDS, applies bias+sigmoid+avgpool2, stores.
template <int XFP32>
__device__ __forceinline__ void gemm_phase(
    const float* __restrict__ Wf, const float* __restrict__ bias,
    const void* __restrict__ Xv, void* __restrict__ Y,
    const int K, const int Np, const int out_bf16,
    const int i_base, const int b_base, SmemG* sm, const int tid) {
  const int srow = tid >> 3, sseg = tid & 7;   // W stage: 64 rows x 8 segs of 16
  const int xr = tid >> 5, xs = tid & 31;      // X stage: 16 rows x 32 segs of 4
  const int w = tid >> 6, lane = tid & 63;
  const int rgrp = w >> 1, kg = w & 1;
  const int L15 = lane & 15, q = lane >> 4;
  const float* Xf = (const float*)Xv;
  const unsigned short* Xh = (const unsigned short*)Xv;

  float4 wf[2][4];
  float4 xf[2];
  uint2 xh2[2];

#define LOADW(S, KO)                                                          \
  do {                                                                        \
    _Pragma("unroll") for (int j = 0; j < 4; j++)                             \
        wf[S][j] = *(const float4*)&Wf[(size_t)(i_base + srow) * K + (KO) +   \
                                       sseg * 16 + 4 * j];                    \
  } while (0)

#define LOADX(S, KO)                                                          \
  do {                                                                        \
    if (XFP32) {                                                              \
      xf[S] = *(const float4*)&Xf[(size_t)(b_base + xr) * K + (KO) + xs * 4]; \
    } else {                                                                  \
      xh2[S] = *(const uint2*)&Xh[(size_t)(b_base + xr) * K + (KO) + xs * 4]; \
    }                                                                         \
  } while (0)

#define STAGEW(S)                                                             \
  do {                                                                        \
    uint4 p0 = {pack2bf(wf[S][0].x, wf[S][0].y),                              \
                pack2bf(wf[S][0].z, wf[S][0].w),                              \
                pack2bf(wf[S][1].x, wf[S][1].y),                              \
                pack2bf(wf[S][1].z, wf[S][1].w)};                             \
    uint4 p1 = {pack2bf(wf[S][2].x, wf[S][2].y),                              \
                pack2bf(wf[S][2].z, wf[S][2].w),                              \
                pack2bf(wf[S][3].x, wf[S][3].y),                              \
                pack2bf(wf[S][3].z, wf[S][3].w)};                             \
    *(uint4*)&sm->Wt[srow][sseg * 16] = p0;                                   \
    *(uint4*)&sm->Wt[srow][sseg * 16 + 8] = p1;                               \
  } while (0)

#define STAGEX(S)                                                             \
  do {                                                                        \
    if (XFP32) {                                                              \
      uint2 p = {pack2bf(xf[S].x, xf[S].y), pack2bf(xf[S].z, xf[S].w)};       \
      *(uint2*)&sm->Xt[xr][xs * 4] = p;                                       \
    } else {                                                                  \
      *(uint2*)&sm->Xt[xr][xs * 4] = xh2[S];                                  \
    }                                                                         \
  } while (0)

#define DOMFMA                                                                \
  do {                                                                        \
    _Pragma("unroll") for (int tki = 0; tki < 2; tki++) {                     \
      const int kt = kg * 2 + tki;                                            \
      bf16x8 a = *(const bf16x8*)&sm->Wt[rgrp * 16 + L15][kt * 32 + q * 8];   \
      bf16x8 bb = *(const bf16x8*)&sm->Xt[L15][kt * 32 + q * 8];              \
      acc = __builtin_amdgcn_mfma_f32_16x16x32_bf16(a, bb, acc, 0, 0, 0);     \
    }                                                                         \
  } while (0)

  f32x4 acc = {};
  LOADW(0, 0);
  LOADX(0, 0);
  for (int k0 = 0; k0 < K; k0 += 256) {  // K is a multiple of 256
    // body A: compute slab k0 (slot 0), prefetch k0+128 (slot 1)
    LOADW(1, k0 + 128);
    LOADX(1, k0 + 128);
    STAGEW(0);
    STAGEX(0);
    __syncthreads();
    DOMFMA;
    __syncthreads();
    // body B: compute slab k0+128 (slot 1), prefetch k0+256 (slot 0)
    if (k0 + 256 < K) {
      LOADW(0, k0 + 256);
      LOADX(0, k0 + 256);
    }
    STAGEW(1);
    STAGEX(1);
    __syncthreads();
    DOMFMA;
    __syncthreads();
  }
#undef LOADW
#undef LOADX
#undef STAGEW
#undef STAGEX
#undef DOMFMA

  // merge K-group partials, then epilogue on kg==0 waves
  if (kg == 1) *(f32x4*)&sm->racc[rgrp][lane][0] = acc;
  __syncthreads();
  if (kg == 0) {
    acc += *(const f32x4*)&sm->racc[rgrp][lane][0];
    const int nrow = i_base + rgrp * 16 + q * 4;
    const float bi0 = bias[nrow], bi1 = bias[nrow + 1];
    const float bi2 = bias[nrow + 2], bi3 = bias[nrow + 3];
    const int b = b_base + L15;
    const float a0 = __builtin_amdgcn_rcpf(1.f + __expf(-(acc[0] + bi0)));
    const float a1 = __builtin_amdgcn_rcpf(1.f + __expf(-(acc[1] + bi1)));
    const float a2 = __builtin_amdgcn_rcpf(1.f + __expf(-(acc[2] + bi2)));
    const float a3 = __builtin_amdgcn_rcpf(1.f + __expf(-(acc[3] + bi3)));
    const float p0 = 0.5f * (a0 + a1), p1 = 0.5f * (a2 + a3);
    const int pidx = nrow >> 1;  // even
    if (out_bf16) {
      *(unsigned int*)&((unsigned short*)Y)[(size_t)b * Np + pidx] = pack2bf(p0, p1);
    } else {
      *(float2*)&((float*)Y)[(size_t)b * Np + pidx] = make_float2(p0, p1);
    }
  }
  __syncthreads();  // protect smem reuse by the next phase
}

// ---------- fused cooperative kernel ----------
// phase0 prep P -> sync -> phase1 gemm1 (256 blk) -> sync ->
// phase2 gemm2 (blk 0..127) -> sync -> phase3 lstm (1 batch/blk).
// LSTM body is the proven R21/R22 structure (133.5us), verbatim.
__global__ __launch_bounds__(512, 2) void fused_all(
    const float* __restrict__ x, const float* __restrict__ W1L,
    const float* __restrict__ b1L, const float* __restrict__ W2L,
    const float* __restrict__ b2L, const float* __restrict__ Wih,
    const float* __restrict__ Whh, const float* __restrict__ b3,
    const float* __restrict__ Wout, const float* __restrict__ bout,
    unsigned short* __restrict__ xl1b, float* __restrict__ xl2,
    _Float16* __restrict__ P, float* __restrict__ out) {
  __shared__ __align__(16) SmemU smem;
  const int t = threadIdx.x;
  const int blk = blockIdx.x;
  cg::grid_group grid = cg::this_grid();

  // ---- phase 0: prep P (Whh -> f16, hid-interleaved, exp2-prescaled) ----
  {
    const int idx = blk * 512 + t;
    if (idx < 400 * 16) {
      const int row = idx >> 4, ch = idx & 15;
      const int hid = row >> 2, gate = row & 3;
      const int src = gate * 100 + hid;
      const float s = (gate == 2) ? TWOL2E : LOG2E;
      f16x8 v;
#pragma unroll
      for (int j = 0; j < 8; j++) {
        const int k = ch * 8 + j;
        float f = 0.f;
        if (k < 100) f = Whh[(size_t)src * 100 + k] * s;
        v[j] = (_Float16)f;
      }
      *(f16x8*)&P[(size_t)row * 128 + ch * 8] = v;
    }
  }
  __threadfence();
  grid.sync();

  // ---- phase 1: gemm1 -- 1024x1024 W, 16 row-tiles x 16 batch-tiles ----
  gemm_phase<1>(W1L, b1L, x, xl1b, 1024, 512, 1,
                (blk >> 4) * 64, (blk & 15) * 16, &smem.g, t);
  __threadfence();
  grid.sync();

  // ---- phase 2: gemm2 -- 512x512 W, 8 row-tiles x 16 batch-tiles ----
  if (blk < 128)
    gemm_phase<0>(W2L, b2L, xl1b, xl2, 512, 256, 0,
                  (blk >> 4) * 64, (blk & 15) * 16, &smem.g, t);
  __threadfence();
  grid.sync();

  // ---- phase 3: LSTM, batch = blk ----
  {
    const int bat = blk;
    const int w = t >> 6, lane = t & 63;
    const int quad = lane >> 4, c = lane & 15;
    const int TB = (w == 7) ? 21 : w * 3;   // tile base
    const int NT = (w == 7) ? 4 : 3;        // tiles this wave activates

    _Float16* h0 = smem.l.hbuf[0];
    _Float16* h1 = smem.l.hbuf[1];
    float* xrow = smem.l.xrow;
    float* red = smem.l.red;

    for (int i = t; i < TSTEPS; i += 512) xrow[i] = xl2[(size_t)bat * TSTEPS + i];
    if (t < 128) { h0[t] = (_Float16)0.f; h1[t] = (_Float16)0.f; }

#define LDA(J, KT) const f16x8 A##J##KT = \
    *(const f16x8*)&P[(size_t)((TB + J) * 16 + c) * 128 + (KT) * 32 + quad * 8];
    LDA(0,0) LDA(0,1) LDA(0,2)
    LDA(1,0) LDA(1,1) LDA(1,2)
    LDA(2,0) LDA(2,1) LDA(2,2)
    LDA(3,0) LDA(3,1) LDA(3,2)
#undef LDA

    const bool act = (c < 4 * NT);
    const int J = c >> 2, g = c & 3;
    const int myhid = 4 * (TB + (act ? J : 0)) + quad;  // < 100
    const int grow = g * 100 + myhid;                   // gate-major row
    const float sc = (g == 2) ? TWOL2E : LOG2E;         // exp2 prescale
    const float u_ = Wih[grow] * sc;
    const float bz = b3[grow] * sc;
    const float4 wt0 = *(const float4*)&Whh[(size_t)grow * 100 + 96];
    const float4 wt = make_float4(wt0.x * sc, wt0.y * sc, wt0.z * sc, wt0.w * sc);
    const float mm = (g == 2) ? 2.f : 1.f;
    const float dd = (g == 2) ? -1.f : 0.f;
    float cst = 0.f;
    __syncthreads();

#define SIG2(zz) __builtin_amdgcn_rcpf(1.f + __builtin_amdgcn_exp2f(-(zz)))
#define STEPB(HC, HN, XT)                                                      \
  {                                                                            \
    const _Float16* hc = (HC);                                                 \
    const f16x8 B0 = *(const f16x8*)&hc[0 * 32 + quad * 8];                    \
    const f16x8 B1 = *(const f16x8*)&hc[1 * 32 + quad * 8];                    \
    const f16x8 B2 = *(const f16x8*)&hc[2 * 32 + quad * 8];                    \
    f32x4 z0 = {0.f,0.f,0.f,0.f}, z1 = z0, z2 = z0, z3 = z0;                   \
    { f32x4 za = z0, zb = z0;                                                  \
      za = __builtin_amdgcn_mfma_f32_16x16x32_f16(A00, B0, za, 0, 0, 0);       \
      zb = __builtin_amdgcn_mfma_f32_16x16x32_f16(A01, B1, zb, 0, 0, 0);       \
      za = __builtin_amdgcn_mfma_f32_16x16x32_f16(A02, B2, za, 0, 0, 0);       \
      z0 = za + zb; }                                                          \
    { f32x4 za = {0.f,0.f,0.f,0.f}, zb = za;                                   \
      za = __builtin_amdgcn_mfma_f32_16x16x32_f16(A10, B0, za, 0, 0, 0);       \
      zb = __builtin_amdgcn_mfma_f32_16x16x32_f16(A11, B1, zb, 0, 0, 0);       \
      za = __builtin_amdgcn_mfma_f32_16x16x32_f16(A12, B2, za, 0, 0, 0);       \
      z1 = za + zb; }                                                          \
    { f32x4 za = {0.f,0.f,0.f,0.f}, zb = za;                                   \
      za = __builtin_amdgcn_mfma_f32_16x16x32_f16(A20, B0, za, 0, 0, 0);       \
      zb = __builtin_amdgcn_mfma_f32_16x16x32_f16(A21, B1, zb, 0, 0, 0);       \
      za = __builtin_amdgcn_mfma_f32_16x16x32_f16(A22, B2, za, 0, 0, 0);       \
      z2 = za + zb; }                                                          \
    if (w == 7) {                                                              \
      f32x4 za = {0.f,0.f,0.f,0.f}, zb = za;                                   \
      za = __builtin_amdgcn_mfma_f32_16x16x32_f16(A30, B0, za, 0, 0, 0);       \
      zb = __builtin_amdgcn_mfma_f32_16x16x32_f16(A31, B1, zb, 0, 0, 0);       \
      za = __builtin_amdgcn_mfma_f32_16x16x32_f16(A32, B2, za, 0, 0, 0);       \
      z3 = za + zb; }                                                          \
    if (act) {                                                                 \
      const f32x4 zt = (J == 0) ? z0 : (J == 1) ? z1 : (J == 2) ? z2 : z3;     \
      float zs = (g == 0) ? zt[0] : (g == 1) ? zt[1] : (g == 2) ? zt[2] : zt[3];\
      const f16x4 ht = *(const f16x4*)&hc[96];                                 \
      zs = fmaf(wt.x, (float)ht[0], zs);                                       \
      zs = fmaf(wt.y, (float)ht[1], zs);                                       \
      zs = fmaf(wt.z, (float)ht[2], zs);                                       \
      zs = fmaf(wt.w, (float)ht[3], zs);                                       \
      zs = fmaf(u_, (XT), zs + bz);                                            \
      const float a = mm * SIG2(zs) + dd;                                      \
      const float ai = qb0(a), af = qb1(a), ag = qb2(a), ao = qb3(a);          \
      cst = fmaf(af, cst, ai * ag);                                            \
      const float th = 2.f * SIG2(TWOL2E * cst) - 1.f;                         \
      if (g == 0) (HN)[myhid] = (_Float16)(ao * th);                           \
    }                                                                          \
    __syncthreads();                                                           \
  }

    for (int step = 0; step < TSTEPS; step += 2) {
      STEPB(h0, h1, xrow[step]);
      STEPB(h1, h0, xrow[step + 1]);
    }
#undef STEPB
#undef SIG2

    // out[bat] = dot(h_final, Wout) + bout; final h in h0
    if (t < 128) {
      float a = 0.f;
      if (t < 100) a = (float)h0[t] * Wout[t];
      red[t] = a;
    }
    __syncthreads();
    if (t == 0) {
      float s = 0.f;
#pragma unroll
      for (int k = 0; k < 128; k++) s += red[k];
      out[bat] = s + bout[0];
    }
  }
}

// ---------- launch ----------
extern "C" void kernel_launch(void* const* d_in, const int* in_sizes, int n_in,
                              void* d_out, int out_size, void* d_ws, size_t ws_size,
                              hipStream_t stream) {
  const float* x    = (const float*)d_in[0];   // (256,1024)
  const float* W1L  = (const float*)d_in[3];   // (1024,1024)
  const float* b1L  = (const float*)d_in[4];
  const float* W2L  = (const float*)d_in[7];   // (512,512)
  const float* b2L  = (const float*)d_in[8];
  const float* Wih3 = (const float*)d_in[15];  // (400,1)
  const float* Whh3 = (const float*)d_in[16];  // (400,100)
  const float* b3   = (const float*)d_in[17];  // (400,)
  const float* Wout = (const float*)d_in[18];  // (1,100)
  const float* bout = (const float*)d_in[19];  // (1,)
  float* out = (float*)d_out;                  // (256,)

  unsigned short* xl1b = (unsigned short*)d_ws;        // 256x512 bf16
  float* xl2 = (float*)(xl1b + (size_t)256 * 512);     // 256x256 f32
  _Float16* P = (_Float16*)(xl2 + (size_t)256 * 256);  // 400x128 fp16

  void* args[] = {&x, &W1L, &b1L, &W2L, &b2L, &Wih3, &Whh3, &b3,
                  &Wout, &bout, &xl1b, &xl2, &P, &out};
  hipLaunchCooperativeKernel(fused_all, dim3(256), dim3(512), args, 0u, stream);
}

// Round 8
// 304.819 us; speedup vs baseline: 1.4738x; 1.4738x over previous
//
#include <hip/hip_runtime.h>
#include <math.h>

typedef __bf16 bf16x8 __attribute__((ext_vector_type(8)));
typedef _Float16 f16x8 __attribute__((ext_vector_type(8)));
typedef _Float16 f16x4 __attribute__((ext_vector_type(4)));
typedef float f32x4 __attribute__((ext_vector_type(4)));

__device__ __forceinline__ unsigned short f2bf(float f) {
  unsigned int u = __builtin_bit_cast(unsigned int, f);
  u += 0x7fffu + ((u >> 16) & 1u);
  return (unsigned short)(u >> 16);
}
__device__ __forceinline__ unsigned int pack2bf(float a, float b) {
  return (unsigned int)f2bf(a) | ((unsigned int)f2bf(b) << 16);
}

// ---------- bf16 MFMA GEMM + sigmoid + avgpool2 (R22, proven) ----------
// R23 post-mortem: cooperative fusion of these into one kernel REGRESSED
// badly (333us fused vs <=97.6 for all separate dispatches incl. overhead):
// grid.sync spin + 1-block/CU co-residency + per-XCD L2 W-replication
// (FETCH 22MB vs ~6 ideal). Kernel boundaries are NOT the bottleneck.
#define GK_PAD2 72
template <int WFP32, int XFP32>
__global__ __launch_bounds__(256) void gemm_mfma_sig_pool(
    const void* __restrict__ Wv, const float* __restrict__ bias,
    const void* __restrict__ Xv, void* __restrict__ Y,
    int K, int Np, int out_bf16) {
  __shared__ unsigned short Wt[64][GK_PAD2];
  __shared__ unsigned short Xt[16][GK_PAD2];
  const int tid = threadIdx.x;
  const int i_base = blockIdx.x * 64;
  const int b_base = blockIdx.y * 16;
  const int srow = tid >> 2, sseg = tid & 3;   // W stage: 64 rows x 4 segs of 16
  const int xr = tid >> 4, xs = tid & 15;      // X stage: 16 rows x 16 segs of 4
  const int wv = tid >> 6, lane = tid & 63;
  const int L15 = lane & 15, q = lane >> 4;

  const float* Wf = (const float*)Wv;
  const float* Xf = (const float*)Xv;
  const unsigned short* Wh = (const unsigned short*)Wv;
  const unsigned short* Xh = (const unsigned short*)Xv;

  float4 wf[2][4];
  uint4 wh[2][2];
  float4 xf[2];
  uint2 xh2[2];

#define LOADW(S, KO)                                                          \
  do {                                                                        \
    if (WFP32) {                                                              \
      _Pragma("unroll") for (int j = 0; j < 4; j++)                           \
          wf[S][j] = *(const float4*)&Wf[(size_t)(i_base + srow) * K + (KO) + \
                                         sseg * 16 + 4 * j];                  \
    } else {                                                                  \
      _Pragma("unroll") for (int j = 0; j < 2; j++)                           \
          wh[S][j] = *(const uint4*)&Wh[(size_t)(i_base + srow) * K + (KO) +  \
                                        sseg * 16 + 8 * j];                   \
    }                                                                         \
  } while (0)

#define LOADX(S, KO)                                                          \
  do {                                                                        \
    if (XFP32) {                                                              \
      xf[S] = *(const float4*)&Xf[(size_t)(b_base + xr) * K + (KO) + xs * 4]; \
    } else {                                                                  \
      xh2[S] = *(const uint2*)&Xh[(size_t)(b_base + xr) * K + (KO) + xs * 4]; \
    }                                                                         \
  } while (0)

#define STAGEW(S)                                                             \
  do {                                                                        \
    if (WFP32) {                                                              \
      uint4 p0 = {pack2bf(wf[S][0].x, wf[S][0].y),                            \
                  pack2bf(wf[S][0].z, wf[S][0].w),                            \
                  pack2bf(wf[S][1].x, wf[S][1].y),                            \
                  pack2bf(wf[S][1].z, wf[S][1].w)};                           \
      uint4 p1 = {pack2bf(wf[S][2].x, wf[S][2].y),                            \
                  pack2bf(wf[S][2].z, wf[S][2].w),                            \
                  pack2bf(wf[S][3].x, wf[S][3].y),                            \
                  pack2bf(wf[S][3].z, wf[S][3].w)};                           \
      *(uint4*)&Wt[srow][sseg * 16] = p0;                                     \
      *(uint4*)&Wt[srow][sseg * 16 + 8] = p1;                                 \
    } else {                                                                  \
      *(uint4*)&Wt[srow][sseg * 16] = wh[S][0];                               \
      *(uint4*)&Wt[srow][sseg * 16 + 8] = wh[S][1];                           \
    }                                                                         \
  } while (0)

#define STAGEX(S)                                                             \
  do {                                                                        \
    if (XFP32) {                                                              \
      uint2 p = {pack2bf(xf[S].x, xf[S].y), pack2bf(xf[S].z, xf[S].w)};       \
      *(uint2*)&Xt[xr][xs * 4] = p;                                           \
    } else {                                                                  \
      *(uint2*)&Xt[xr][xs * 4] = xh2[S];                                      \
    }                                                                         \
  } while (0)

#define DOMFMA                                                                \
  do {                                                                        \
    _Pragma("unroll") for (int kt = 0; kt < 2; kt++) {                        \
      bf16x8 a = *(const bf16x8*)&Wt[wv * 16 + L15][kt * 32 + q * 8];         \
      bf16x8 b = *(const bf16x8*)&Xt[L15][kt * 32 + q * 8];                   \
      acc = __builtin_amdgcn_mfma_f32_16x16x32_bf16(a, b, acc, 0, 0, 0);      \
    }                                                                         \
  } while (0)

  f32x4 acc = {};
  LOADW(0, 0);
  LOADX(0, 0);
  for (int k0 = 0; k0 < K; k0 += 128) {
    LOADW(1, k0 + 64);  // k0+64 < K always (K multiple of 128)
    LOADX(1, k0 + 64);
    STAGEW(0);
    STAGEX(0);
    __syncthreads();
    DOMFMA;
    __syncthreads();
    if (k0 + 128 < K) {
      LOADW(0, k0 + 128);
      LOADX(0, k0 + 128);
    }
    STAGEW(1);
    STAGEX(1);
    __syncthreads();
    DOMFMA;
    __syncthreads();
  }
#undef LOADW
#undef LOADX
#undef STAGEW
#undef STAGEX
#undef DOMFMA

  // epilogue: rows i_base+16*wv+q*4 .. +3, batch col b_base+L15
  {
    const int nrow = i_base + 16 * wv + q * 4;
    const float bi0 = bias[nrow], bi1 = bias[nrow + 1];
    const float bi2 = bias[nrow + 2], bi3 = bias[nrow + 3];
    const int b = b_base + L15;
    const float a0 = __builtin_amdgcn_rcpf(1.f + __expf(-(acc[0] + bi0)));
    const float a1 = __builtin_amdgcn_rcpf(1.f + __expf(-(acc[1] + bi1)));
    const float a2 = __builtin_amdgcn_rcpf(1.f + __expf(-(acc[2] + bi2)));
    const float a3 = __builtin_amdgcn_rcpf(1.f + __expf(-(acc[3] + bi3)));
    const float p0 = 0.5f * (a0 + a1), p1 = 0.5f * (a2 + a3);
    const int pidx = nrow >> 1;  // even
    if (out_bf16) {
      *(unsigned int*)&((unsigned short*)Y)[(size_t)b * Np + pidx] = pack2bf(p0, p1);
    } else {
      *(float2*)&((float*)Y)[(size_t)b * Np + pidx] = make_float2(p0, p1);
    }
  }
}

// ---------- prep: Whh -> fp16, hid-interleaved rows, K-stride 128 ----------
#define LOG2E 1.44269504f
#define TWOL2E 2.88539008f
__global__ __launch_bounds__(256) void prep_whh(
    const float* __restrict__ Whh, const float* __restrict__ b3,
    _Float16* __restrict__ P) {
  const int idx = blockIdx.x * 256 + threadIdx.x;  // (row, chunk-of-8)
  if (idx >= 400 * 16) return;
  const int row = idx >> 4, ch = idx & 15;
  const int hid = row >> 2, gate = row & 3;
  const int src = gate * 100 + hid;
  const float s = (gate == 2) ? TWOL2E : LOG2E;
  f16x8 v;
#pragma unroll
  for (int j = 0; j < 8; j++) {
    const int k = ch * 8 + j;
    float f = 0.f;
    if (k < 100) f = Whh[(size_t)src * 100 + k] * s;
    v[j] = (_Float16)f;
  }
  *(f16x8*)&P[(size_t)row * 128 + ch * 8] = v;
}

// ---------- MFMA LSTM (R24): 2 batches per 1024-thread block ----------
// R22 counters: 1 block/CU (Occ 22%), step = 1250cy but serial chain +
// per-SIMD issue account for only ~500-600cy -> ~700cy/step of bubbles.
// R24: grid 128 x 1024 threads; waves 0-7 run batch 2*blk with the EXACT
// proven per-batch structure, waves 8-15 run batch 2*blk+1. Independent
// work shares one barrier: when one batch-group sits in its serial act
// chain, the other issues MFMA/ds_read into the same SIMD's bubbles.
// Issue/SIMD doubles (~800-1000cy) but stays under the 1250cy step budget.
// (Unlike R18's failed wave-add: that was the dense structure, trans-
// saturated per CU; this one is bubble-dominated.)
#define TSTEPS 256

__device__ __forceinline__ float qb0(float x) {
  return __builtin_bit_cast(float, __builtin_amdgcn_mov_dpp(__builtin_bit_cast(int, x), 0x00, 0xf, 0xf, true));
}
__device__ __forceinline__ float qb1(float x) {
  return __builtin_bit_cast(float, __builtin_amdgcn_mov_dpp(__builtin_bit_cast(int, x), 0x55, 0xf, 0xf, true));
}
__device__ __forceinline__ float qb2(float x) {
  return __builtin_bit_cast(float, __builtin_amdgcn_mov_dpp(__builtin_bit_cast(int, x), 0xAA, 0xf, 0xf, true));
}
__device__ __forceinline__ float qb3(float x) {
  return __builtin_bit_cast(float, __builtin_amdgcn_mov_dpp(__builtin_bit_cast(int, x), 0xFF, 0xf, 0xf, true));
}

__global__ __launch_bounds__(1024, 1) void lstm_mfma2(
    const float* __restrict__ X, const _Float16* __restrict__ P,
    const float* __restrict__ Whh, const float* __restrict__ Wih,
    const float* __restrict__ b3, const float* __restrict__ Wout,
    const float* __restrict__ bout, float* __restrict__ out) {
  const int bat0 = blockIdx.x * 2;
  const int t = threadIdx.x;
  const int w16 = t >> 6;          // 0..15
  const int wb = w16 >> 3;         // batch-group 0/1
  const int w = w16 & 7;           // role within batch (as in the 8-wave kernel)
  const int lane = t & 63;
  const int quad = lane >> 4, c = lane & 15;
  const int TB = (w == 7) ? 21 : w * 3;   // tile base
  const int NT = (w == 7) ? 4 : 3;        // tiles this wave activates

  __shared__ __align__(16) _Float16 hbuf[2][2][128];  // [batch][buf][hid]
  __shared__ float xrow[2][TSTEPS];
  __shared__ float red[2][128];

  for (int i = t; i < 2 * TSTEPS; i += 1024) {
    const int bb = i >> 8, s = i & 255;
    xrow[bb][s] = X[(size_t)(bat0 + bb) * TSTEPS + s];
  }
  if (t < 512) ((_Float16*)hbuf)[t] = (_Float16)0.f;

  // 12 A-fragments (identical for both batch-groups; L1-served)
#define LDA(J, KT) const f16x8 A##J##KT = \
    *(const f16x8*)&P[(size_t)((TB + J) * 16 + c) * 128 + (KT) * 32 + quad * 8];
  LDA(0,0) LDA(0,1) LDA(0,2)
  LDA(1,0) LDA(1,1) LDA(1,2)
  LDA(2,0) LDA(2,1) LDA(2,2)
  LDA(3,0) LDA(3,1) LDA(3,2)
#undef LDA

  // activation role: lane handles gate g of hid 4*(TB+J)+quad (within wb)
  const bool act = (c < 4 * NT);
  const int J = c >> 2, g = c & 3;
  const int myhid = 4 * (TB + (act ? J : 0)) + quad;  // < 100
  const int grow = g * 100 + myhid;                   // gate-major row
  const float sc = (g == 2) ? TWOL2E : LOG2E;         // exp2 prescale
  const float u_ = Wih[grow] * sc;
  const float bz = b3[grow] * sc;
  const float4 wt0 = *(const float4*)&Whh[(size_t)grow * 100 + 96];  // k 96..99
  const float4 wt = make_float4(wt0.x * sc, wt0.y * sc, wt0.z * sc, wt0.w * sc);
  const float mm = (g == 2) ? 2.f : 1.f;   // g-gate is tanh = 2*sig(2z)-1
  const float dd = (g == 2) ? -1.f : 0.f;
  float cst = 0.f;

  _Float16* const hb0 = hbuf[wb][0];
  _Float16* const hb1 = hbuf[wb][1];
  const float* const xw = xrow[wb];
  __syncthreads();

#define SIG2(zz) __builtin_amdgcn_rcpf(1.f + __builtin_amdgcn_exp2f(-(zz)))
#define STEPB(HC, HN, XT)                                                      \
  {                                                                            \
    const _Float16* hc = (HC);                                                 \
    const f16x8 B0 = *(const f16x8*)&hc[0 * 32 + quad * 8];                    \
    const f16x8 B1 = *(const f16x8*)&hc[1 * 32 + quad * 8];                    \
    const f16x8 B2 = *(const f16x8*)&hc[2 * 32 + quad * 8];                    \
    f32x4 z0 = {0.f,0.f,0.f,0.f}, z1 = z0, z2 = z0, z3 = z0;                   \
    { f32x4 za = z0, zb = z0;                                                  \
      za = __builtin_amdgcn_mfma_f32_16x16x32_f16(A00, B0, za, 0, 0, 0);       \
      zb = __builtin_amdgcn_mfma_f32_16x16x32_f16(A01, B1, zb, 0, 0, 0);       \
      za = __builtin_amdgcn_mfma_f32_16x16x32_f16(A02, B2, za, 0, 0, 0);       \
      z0 = za + zb; }                                                          \
    { f32x4 za = {0.f,0.f,0.f,0.f}, zb = za;                                   \
      za = __builtin_amdgcn_mfma_f32_16x16x32_f16(A10, B0, za, 0, 0, 0);       \
      zb = __builtin_amdgcn_mfma_f32_16x16x32_f16(A11, B1, zb, 0, 0, 0);       \
      za = __builtin_amdgcn_mfma_f32_16x16x32_f16(A12, B2, za, 0, 0, 0);       \
      z1 = za + zb; }                                                          \
    { f32x4 za = {0.f,0.f,0.f,0.f}, zb = za;                                   \
      za = __builtin_amdgcn_mfma_f32_16x16x32_f16(A20, B0, za, 0, 0, 0);       \
      zb = __builtin_amdgcn_mfma_f32_16x16x32_f16(A21, B1, zb, 0, 0, 0);       \
      za = __builtin_amdgcn_mfma_f32_16x16x32_f16(A22, B2, za, 0, 0, 0);       \
      z2 = za + zb; }                                                          \
    if (w == 7) {                                                              \
      f32x4 za = {0.f,0.f,0.f,0.f}, zb = za;                                   \
      za = __builtin_amdgcn_mfma_f32_16x16x32_f16(A30, B0, za, 0, 0, 0);       \
      zb = __builtin_amdgcn_mfma_f32_16x16x32_f16(A31, B1, zb, 0, 0, 0);       \
      za = __builtin_amdgcn_mfma_f32_16x16x32_f16(A32, B2, za, 0, 0, 0);       \
      z3 = za + zb; }                                                          \
    if (act) {                                                                 \
      const f32x4 zt = (J == 0) ? z0 : (J == 1) ? z1 : (J == 2) ? z2 : z3;     \
      float zs = (g == 0) ? zt[0] : (g == 1) ? zt[1] : (g == 2) ? zt[2] : zt[3];\
      const f16x4 ht = *(const f16x4*)&hc[96];                                 \
      zs = fmaf(wt.x, (float)ht[0], zs);                                       \
      zs = fmaf(wt.y, (float)ht[1], zs);                                       \
      zs = fmaf(wt.z, (float)ht[2], zs);                                       \
      zs = fmaf(wt.w, (float)ht[3], zs);                                       \
      zs = fmaf(u_, (XT), zs + bz);                                            \
      const float a = mm * SIG2(zs) + dd;                                      \
      const float ai = qb0(a), af = qb1(a), ag = qb2(a), ao = qb3(a);          \
      cst = fmaf(af, cst, ai * ag);                                            \
      const float th = 2.f * SIG2(TWOL2E * cst) - 1.f;                         \
      if (g == 0) (HN)[myhid] = (_Float16)(ao * th);                           \
    }                                                                          \
    __syncthreads();                                                           \
  }

  for (int step = 0; step < TSTEPS; step += 2) {
    STEPB(hb0, hb1, xw[step]);
    STEPB(hb1, hb0, xw[step + 1]);
  }
#undef STEPB
#undef SIG2

  // out[bat0+b] = dot(h_final, Wout) + bout; final h in hbuf[b][0]
  if (t < 256) {
    const int bb = t >> 7, j = t & 127;
    float a = 0.f;
    if (j < 100) a = (float)hbuf[bb][0][j] * Wout[j];
    red[bb][j] = a;
  }
  __syncthreads();
  if (t < 2) {
    float s = 0.f;
#pragma unroll
    for (int k = 0; k < 128; k++) s += red[t][k];
    out[bat0 + t] = s + bout[0];
  }
}

// ---------- launch ----------
extern "C" void kernel_launch(void* const* d_in, const int* in_sizes, int n_in,
                              void* d_out, int out_size, void* d_ws, size_t ws_size,
                              hipStream_t stream) {
  const float* x    = (const float*)d_in[0];   // (256,1024)
  const float* W1L  = (const float*)d_in[3];   // (1024,1024)
  const float* b1L  = (const float*)d_in[4];
  const float* W2L  = (const float*)d_in[7];   // (512,512)
  const float* b2L  = (const float*)d_in[8];
  const float* Wih3 = (const float*)d_in[15];  // (400,1)
  const float* Whh3 = (const float*)d_in[16];  // (400,100)
  const float* b3   = (const float*)d_in[17];  // (400,)
  const float* Wout = (const float*)d_in[18];  // (1,100)
  const float* bout = (const float*)d_in[19];  // (1,)
  float* out = (float*)d_out;                  // (256,)

  unsigned short* xl1b = (unsigned short*)d_ws;        // 256x512 bf16
  float* xl2 = (float*)(xl1b + (size_t)256 * 512);     // 256x256 f32
  _Float16* P = (_Float16*)(xl2 + (size_t)256 * 256);  // 400x128 fp16

  prep_whh<<<25, 256, 0, stream>>>(Whh3, b3, P);
  gemm_mfma_sig_pool<1, 1><<<dim3(16, 16), 256, 0, stream>>>(W1L, b1L, x, xl1b, 1024, 512, 1);
  gemm_mfma_sig_pool<1, 0><<<dim3(8, 16), 256, 0, stream>>>(W2L, b2L, xl1b, xl2, 512, 256, 0);
  lstm_mfma2<<<128, 1024, 0, stream>>>(xl2, P, Whh3, Wih3, b3, Wout, bout, out);
}

// Round 9
// 270.958 us; speedup vs baseline: 1.6580x; 1.1250x over previous
//
#include <hip/hip_runtime.h>
#include <math.h>

typedef __bf16 bf16x8 __attribute__((ext_vector_type(8)));
typedef _Float16 f16x8 __attribute__((ext_vector_type(8)));
typedef _Float16 f16x4 __attribute__((ext_vector_type(4)));
typedef float f32x4 __attribute__((ext_vector_type(4)));

#define LOG2E 1.44269504f
#define TWOL2E 2.88539008f

__device__ __forceinline__ unsigned short f2bf(float f) {
  unsigned int u = __builtin_bit_cast(unsigned int, f);
  u += 0x7fffu + ((u >> 16) & 1u);
  return (unsigned short)(u >> 16);
}
__device__ __forceinline__ unsigned int pack2bf(float a, float b) {
  return (unsigned int)f2bf(a) | ((unsigned int)f2bf(b) << 16);
}

// ---------- bf16 MFMA GEMM + sigmoid + avgpool2 ----------
// R25: (a) LDS double-buffer -- stage into lds[s&1] while MFMA reads
// lds[(s-1)&1]; ONE barrier per 64-K stage (was two). Keeps R22's register
// prefetch. (b) gemm1 carries the prep work as 16 extra blocks (x==16):
// one fewer dispatch. R23 showed cooperative mega-fusion regresses badly;
// this is plain same-stream packing, no grid.sync.
#define GK_PAD2 72
template <int WFP32, int XFP32, int DO_PREP>
__global__ __launch_bounds__(256) void gemm_mfma_sig_pool(
    const void* __restrict__ Wv, const float* __restrict__ bias,
    const void* __restrict__ Xv, void* __restrict__ Y,
    int K, int Np, int out_bf16,
    const float* __restrict__ Whh, const float* __restrict__ b3,
    _Float16* __restrict__ P) {
  if (DO_PREP && blockIdx.x == 16) {
    // prep: Whh -> fp16, hid-interleaved rows, K-stride 128, exp2-prescale.
    // 16 y-blocks x 256 threads x 2 items cover 400*16 = 6400 chunks.
    const int base = blockIdx.y * 256 + threadIdx.x;
    for (int idx = base; idx < 400 * 16; idx += 4096) {
      const int row = idx >> 4, ch = idx & 15;
      const int hid = row >> 2, gate = row & 3;
      const int src = gate * 100 + hid;
      const float s = (gate == 2) ? TWOL2E : LOG2E;
      f16x8 v;
#pragma unroll
      for (int j = 0; j < 8; j++) {
        const int k = ch * 8 + j;
        float f = 0.f;
        if (k < 100) f = Whh[(size_t)src * 100 + k] * s;
        v[j] = (_Float16)f;
      }
      *(f16x8*)&P[(size_t)row * 128 + ch * 8] = v;
    }
    return;
  }

  __shared__ unsigned short Wt[2][64][GK_PAD2];
  __shared__ unsigned short Xt[2][16][GK_PAD2];
  const int tid = threadIdx.x;
  const int i_base = blockIdx.x * 64;
  const int b_base = blockIdx.y * 16;
  const int srow = tid >> 2, sseg = tid & 3;   // W stage: 64 rows x 4 segs of 16
  const int xr = tid >> 4, xs = tid & 15;      // X stage: 16 rows x 16 segs of 4
  const int wv = tid >> 6, lane = tid & 63;
  const int L15 = lane & 15, q = lane >> 4;

  const float* Wf = (const float*)Wv;
  const float* Xf = (const float*)Xv;
  const unsigned short* Wh = (const unsigned short*)Wv;
  const unsigned short* Xh = (const unsigned short*)Xv;

  float4 wf[2][4];
  uint4 wh[2][2];
  float4 xf[2];
  uint2 xh2[2];

#define LOADW(S, KO)                                                          \
  do {                                                                        \
    if (WFP32) {                                                              \
      _Pragma("unroll") for (int j = 0; j < 4; j++)                           \
          wf[S][j] = *(const float4*)&Wf[(size_t)(i_base + srow) * K + (KO) + \
                                         sseg * 16 + 4 * j];                  \
    } else {                                                                  \
      _Pragma("unroll") for (int j = 0; j < 2; j++)                           \
          wh[S][j] = *(const uint4*)&Wh[(size_t)(i_base + srow) * K + (KO) +  \
                                        sseg * 16 + 8 * j];                   \
    }                                                                         \
  } while (0)

#define LOADX(S, KO)                                                          \
  do {                                                                        \
    if (XFP32) {                                                              \
      xf[S] = *(const float4*)&Xf[(size_t)(b_base + xr) * K + (KO) + xs * 4]; \
    } else {                                                                  \
      xh2[S] = *(const uint2*)&Xh[(size_t)(b_base + xr) * K + (KO) + xs * 4]; \
    }                                                                         \
  } while (0)

#define STAGEW(S, PB)                                                         \
  do {                                                                        \
    if (WFP32) {                                                              \
      uint4 p0 = {pack2bf(wf[S][0].x, wf[S][0].y),                            \
                  pack2bf(wf[S][0].z, wf[S][0].w),                            \
                  pack2bf(wf[S][1].x, wf[S][1].y),                            \
                  pack2bf(wf[S][1].z, wf[S][1].w)};                           \
      uint4 p1 = {pack2bf(wf[S][2].x, wf[S][2].y),                            \
                  pack2bf(wf[S][2].z, wf[S][2].w),                            \
                  pack2bf(wf[S][3].x, wf[S][3].y),                            \
                  pack2bf(wf[S][3].z, wf[S][3].w)};                           \
      *(uint4*)&Wt[PB][srow][sseg * 16] = p0;                                 \
      *(uint4*)&Wt[PB][srow][sseg * 16 + 8] = p1;                             \
    } else {                                                                  \
      *(uint4*)&Wt[PB][srow][sseg * 16] = wh[S][0];                           \
      *(uint4*)&Wt[PB][srow][sseg * 16 + 8] = wh[S][1];                       \
    }                                                                         \
  } while (0)

#define STAGEX(S, PB)                                                         \
  do {                                                                        \
    if (XFP32) {                                                              \
      uint2 p = {pack2bf(xf[S].x, xf[S].y), pack2bf(xf[S].z, xf[S].w)};       \
      *(uint2*)&Xt[PB][xr][xs * 4] = p;                                       \
    } else {                                                                  \
      *(uint2*)&Xt[PB][xr][xs * 4] = xh2[S];                                  \
    }                                                                         \
  } while (0)

#define DOMFMA(PB)                                                            \
  do {                                                                        \
    _Pragma("unroll") for (int kt = 0; kt < 2; kt++) {                        \
      bf16x8 a = *(const bf16x8*)&Wt[PB][wv * 16 + L15][kt * 32 + q * 8];     \
      bf16x8 b = *(const bf16x8*)&Xt[PB][L15][kt * 32 + q * 8];               \
      acc = __builtin_amdgcn_mfma_f32_16x16x32_bf16(a, b, acc, 0, 0, 0);      \
    }                                                                         \
  } while (0)

  f32x4 acc = {};
  const int S = K >> 6;  // 64-K stages (16 for K=1024, 8 for K=512)
  LOADW(0, 0);
  LOADX(0, 0);
  STAGEW(0, 0);
  STAGEX(0, 0);
  LOADW(1, 64);
  LOADX(1, 64);
  __syncthreads();
  for (int s = 1; s < S; s++) {
    STAGEW(s & 1, s & 1);
    STAGEX(s & 1, s & 1);
    if (s + 1 < S) {
      LOADW((s + 1) & 1, 64 * (s + 1));
      LOADX((s + 1) & 1, 64 * (s + 1));
    }
    DOMFMA((s - 1) & 1);
    __syncthreads();
  }
  DOMFMA((S - 1) & 1);
#undef LOADW
#undef LOADX
#undef STAGEW
#undef STAGEX
#undef DOMFMA

  // epilogue: rows i_base+16*wv+q*4 .. +3, batch col b_base+L15
  {
    const int nrow = i_base + 16 * wv + q * 4;
    const float bi0 = bias[nrow], bi1 = bias[nrow + 1];
    const float bi2 = bias[nrow + 2], bi3 = bias[nrow + 3];
    const int b = b_base + L15;
    const float a0 = __builtin_amdgcn_rcpf(1.f + __expf(-(acc[0] + bi0)));
    const float a1 = __builtin_amdgcn_rcpf(1.f + __expf(-(acc[1] + bi1)));
    const float a2 = __builtin_amdgcn_rcpf(1.f + __expf(-(acc[2] + bi2)));
    const float a3 = __builtin_amdgcn_rcpf(1.f + __expf(-(acc[3] + bi3)));
    const float p0 = 0.5f * (a0 + a1), p1 = 0.5f * (a2 + a3);
    const int pidx = nrow >> 1;  // even
    if (out_bf16) {
      *(unsigned int*)&((unsigned short*)Y)[(size_t)b * Np + pidx] = pack2bf(p0, p1);
    } else {
      *(float2*)&((float*)Y)[(size_t)b * Np + pidx] = make_float2(p0, p1);
    }
  }
}

// ---------- MFMA LSTM (byte-identical to R22's measured 133.5us) ----------
// Frozen: R17 dense (205), R18 16-wave (200), R20 tail-fold (145), R24
// dual-batch (206) all regressed vs this structure. Step is barrier+LDS
// roundtrip latency-pinned; barrier cost scales with wave count (8w=540ns,
// 16w=800ns regardless of act density).
#define TSTEPS 256

__device__ __forceinline__ float qb0(float x) {
  return __builtin_bit_cast(float, __builtin_amdgcn_mov_dpp(__builtin_bit_cast(int, x), 0x00, 0xf, 0xf, true));
}
__device__ __forceinline__ float qb1(float x) {
  return __builtin_bit_cast(float, __builtin_amdgcn_mov_dpp(__builtin_bit_cast(int, x), 0x55, 0xf, 0xf, true));
}
__device__ __forceinline__ float qb2(float x) {
  return __builtin_bit_cast(float, __builtin_amdgcn_mov_dpp(__builtin_bit_cast(int, x), 0xAA, 0xf, 0xf, true));
}
__device__ __forceinline__ float qb3(float x) {
  return __builtin_bit_cast(float, __builtin_amdgcn_mov_dpp(__builtin_bit_cast(int, x), 0xFF, 0xf, 0xf, true));
}

__global__ __launch_bounds__(512, 2) void lstm_mfma(
    const float* __restrict__ X, const _Float16* __restrict__ P,
    const float* __restrict__ Whh, const float* __restrict__ Wih,
    const float* __restrict__ b3, const float* __restrict__ Wout,
    const float* __restrict__ bout, float* __restrict__ out) {
  const int bat = blockIdx.x;
  const int t = threadIdx.x;
  const int w = t >> 6, lane = t & 63;
  const int quad = lane >> 4, c = lane & 15;
  const int TB = (w == 7) ? 21 : w * 3;   // tile base
  const int NT = (w == 7) ? 4 : 3;        // tiles this wave activates

  __shared__ __align__(16) _Float16 hbuf[2][128];
  __shared__ float xrow[TSTEPS];
  __shared__ float red[128];

  for (int i = t; i < TSTEPS; i += 512) xrow[i] = X[(size_t)bat * TSTEPS + i];
  if (t < 128) { hbuf[0][t] = (_Float16)0.f; hbuf[1][t] = (_Float16)0.f; }

#define LDA(J, KT) const f16x8 A##J##KT = \
    *(const f16x8*)&P[(size_t)((TB + J) * 16 + c) * 128 + (KT) * 32 + quad * 8];
  LDA(0,0) LDA(0,1) LDA(0,2)
  LDA(1,0) LDA(1,1) LDA(1,2)
  LDA(2,0) LDA(2,1) LDA(2,2)
  LDA(3,0) LDA(3,1) LDA(3,2)
#undef LDA

  // activation role: lane handles gate g of hid 4*(TB+J)+quad
  const bool act = (c < 4 * NT);
  const int J = c >> 2, g = c & 3;
  const int myhid = 4 * (TB + (act ? J : 0)) + quad;  // < 100
  const int grow = g * 100 + myhid;                   // gate-major row
  const float sc = (g == 2) ? TWOL2E : LOG2E;         // exp2 prescale
  const float u_ = Wih[grow] * sc;
  const float bz = b3[grow] * sc;
  const float4 wt0 = *(const float4*)&Whh[(size_t)grow * 100 + 96];  // k 96..99
  const float4 wt = make_float4(wt0.x * sc, wt0.y * sc, wt0.z * sc, wt0.w * sc);
  const float mm = (g == 2) ? 2.f : 1.f;   // g-gate is tanh = 2*sig(2z)-1
  const float dd = (g == 2) ? -1.f : 0.f;
  float cst = 0.f;
  __syncthreads();

#define SIG2(zz) __builtin_amdgcn_rcpf(1.f + __builtin_amdgcn_exp2f(-(zz)))
#define STEPB(HC, HN, XT)                                                      \
  {                                                                            \
    const _Float16* hc = (HC);                                                 \
    const f16x8 B0 = *(const f16x8*)&hc[0 * 32 + quad * 8];                    \
    const f16x8 B1 = *(const f16x8*)&hc[1 * 32 + quad * 8];                    \
    const f16x8 B2 = *(const f16x8*)&hc[2 * 32 + quad * 8];                    \
    f32x4 z0 = {0.f,0.f,0.f,0.f}, z1 = z0, z2 = z0, z3 = z0;                   \
    { f32x4 za = z0, zb = z0;                                                  \
      za = __builtin_amdgcn_mfma_f32_16x16x32_f16(A00, B0, za, 0, 0, 0);       \
      zb = __builtin_amdgcn_mfma_f32_16x16x32_f16(A01, B1, zb, 0, 0, 0);       \
      za = __builtin_amdgcn_mfma_f32_16x16x32_f16(A02, B2, za, 0, 0, 0);       \
      z0 = za + zb; }                                                          \
    { f32x4 za = {0.f,0.f,0.f,0.f}, zb = za;                                   \
      za = __builtin_amdgcn_mfma_f32_16x16x32_f16(A10, B0, za, 0, 0, 0);       \
      zb = __builtin_amdgcn_mfma_f32_16x16x32_f16(A11, B1, zb, 0, 0, 0);       \
      za = __builtin_amdgcn_mfma_f32_16x16x32_f16(A12, B2, za, 0, 0, 0);       \
      z1 = za + zb; }                                                          \
    { f32x4 za = {0.f,0.f,0.f,0.f}, zb = za;                                   \
      za = __builtin_amdgcn_mfma_f32_16x16x32_f16(A20, B0, za, 0, 0, 0);       \
      zb = __builtin_amdgcn_mfma_f32_16x16x32_f16(A21, B1, zb, 0, 0, 0);       \
      za = __builtin_amdgcn_mfma_f32_16x16x32_f16(A22, B2, za, 0, 0, 0);       \
      z2 = za + zb; }                                                          \
    if (w == 7) {                                                              \
      f32x4 za = {0.f,0.f,0.f,0.f}, zb = za;                                   \
      za = __builtin_amdgcn_mfma_f32_16x16x32_f16(A30, B0, za, 0, 0, 0);       \
      zb = __builtin_amdgcn_mfma_f32_16x16x32_f16(A31, B1, zb, 0, 0, 0);       \
      za = __builtin_amdgcn_mfma_f32_16x16x32_f16(A32, B2, za, 0, 0, 0);       \
      z3 = za + zb; }                                                          \
    if (act) {                                                                 \
      const f32x4 zt = (J == 0) ? z0 : (J == 1) ? z1 : (J == 2) ? z2 : z3;     \
      float zs = (g == 0) ? zt[0] : (g == 1) ? zt[1] : (g == 2) ? zt[2] : zt[3];\
      const f16x4 ht = *(const f16x4*)&hc[96];                                 \
      zs = fmaf(wt.x, (float)ht[0], zs);                                       \
      zs = fmaf(wt.y, (float)ht[1], zs);                                       \
      zs = fmaf(wt.z, (float)ht[2], zs);                                       \
      zs = fmaf(wt.w, (float)ht[3], zs);                                       \
      zs = fmaf(u_, (XT), zs + bz);                                            \
      const float a = mm * SIG2(zs) + dd;                                      \
      const float ai = qb0(a), af = qb1(a), ag = qb2(a), ao = qb3(a);          \
      cst = fmaf(af, cst, ai * ag);                                            \
      const float th = 2.f * SIG2(TWOL2E * cst) - 1.f;                         \
      if (g == 0) (HN)[myhid] = (_Float16)(ao * th);                           \
    }                                                                          \
    __syncthreads();                                                           \
  }

  for (int step = 0; step < TSTEPS; step += 2) {
    STEPB(hbuf[0], hbuf[1], xrow[step]);
    STEPB(hbuf[1], hbuf[0], xrow[step + 1]);
  }
#undef STEPB
#undef SIG2

  // out[bat] = dot(h_final, Wout) + bout; final h in hbuf[0]
  if (t < 128) {
    float a = 0.f;
    if (t < 100) a = (float)hbuf[0][t] * Wout[t];
    red[t] = a;
  }
  __syncthreads();
  if (t == 0) {
    float s = 0.f;
#pragma unroll
    for (int k = 0; k < 128; k++) s += red[k];
    out[bat] = s + bout[0];
  }
}

// ---------- launch ----------
extern "C" void kernel_launch(void* const* d_in, const int* in_sizes, int n_in,
                              void* d_out, int out_size, void* d_ws, size_t ws_size,
                              hipStream_t stream) {
  const float* x    = (const float*)d_in[0];   // (256,1024)
  const float* W1L  = (const float*)d_in[3];   // (1024,1024)
  const float* b1L  = (const float*)d_in[4];
  const float* W2L  = (const float*)d_in[7];   // (512,512)
  const float* b2L  = (const float*)d_in[8];
  const float* Wih3 = (const float*)d_in[15];  // (400,1)
  const float* Whh3 = (const float*)d_in[16];  // (400,100)
  const float* b3   = (const float*)d_in[17];  // (400,)
  const float* Wout = (const float*)d_in[18];  // (1,100)
  const float* bout = (const float*)d_in[19];  // (1,)
  float* out = (float*)d_out;                  // (256,)

  unsigned short* xl1b = (unsigned short*)d_ws;        // 256x512 bf16
  float* xl2 = (float*)(xl1b + (size_t)256 * 512);     // 256x256 f32
  _Float16* P = (_Float16*)(xl2 + (size_t)256 * 256);  // 400x128 fp16

  // gemm1 carries prep in its 17th x-block-column
  gemm_mfma_sig_pool<1, 1, 1><<<dim3(17, 16), 256, 0, stream>>>(
      W1L, b1L, x, xl1b, 1024, 512, 1, Whh3, b3, P);
  gemm_mfma_sig_pool<1, 0, 0><<<dim3(8, 16), 256, 0, stream>>>(
      W2L, b2L, xl1b, xl2, 512, 256, 0, nullptr, nullptr, nullptr);
  lstm_mfma<<<256, 512, 0, stream>>>(xl2, P, Whh3, Wih3, b3, Wout, bout, out);
}